// Round 1
// baseline (19806.020 us; speedup 1.0000x reference)
//
#include <hip/hip_runtime.h>
#include <math.h>

// ---------------- problem constants ----------------
constexpr int B_   = 2;
constexpr int CIN  = 512, HI = 64, WI = 128;     // conv-transpose input
constexpr int C_   = 256, H_ = 128, W_ = 256;    // residual stream
constexpr int IMG  = H_ * W_;                    // 32768
constexpr int NWIN = 1024;                       // B * 16 * 32 windows of 8x8
constexpr int QKV_WIN = 3 * 8 * 32 * 64;         // 49152 floats per window (3,head,d,l)

// ---------------- RoPE table: rope[0..2047]=cos, [2048..4095]=sin, idx = l*32+d ----
__global__ __launch_bounds__(256) void k_rope(float* __restrict__ rope) {
    int i = blockIdx.x * 256 + threadIdx.x;
    if (i >= 2048) return;
    int l = i >> 5, d = i & 31;
    int j = d & 15;                 // theta index (cos/sin repeat over halves)
    int ly = l >> 3, lx = l & 7;
    float fr = powf(10000.f, -(float)(j & 7) / 8.f);
    float t = (j < 8 ? (float)ly : (float)lx) * fr;
    rope[i]        = cosf(t);
    rope[2048 + i] = sinf(t);
}

// ---------------- fused dual ConvTranspose2d + concat -> h ----------------
__global__ __launch_bounds__(256) void k_convt(const float* __restrict__ x,
                                               const float* __restrict__ w2,
                                               const float* __restrict__ cb2,
                                               const float* __restrict__ w4,
                                               const float* __restrict__ cb4,
                                               float* __restrict__ h) {
    int idx = blockIdx.x * 256 + threadIdx.x;     // (b, o, oh, ow)
    int ow = idx & 255;
    int oh = (idx >> 8) & 127;
    int o  = (idx >> 15) & 255;
    int b  = idx >> 23;
    const float* xb = x + (size_t)b * CIN * HI * WI;
    float acc;
    if (o < 128) {
        // k=2, s=2, pad=0: exactly one tap
        int kh = oh & 1, kw = ow & 1, ih = oh >> 1, iw = ow >> 1;
        acc = cb2[o];
        const float* xp = xb + ih * WI + iw;
        const float* wp = w2 + (o * 2 + kh) * 2 + kw;   // (CIN,128,2,2), ci-stride 512
        #pragma unroll 4
        for (int ci = 0; ci < CIN; ci++)
            acc += xp[ci * (HI * WI)] * wp[ci * 512];
    } else {
        // k=4, s=2, pad=1: up to 4 taps
        int o2 = o - 128;
        acc = cb4[o2];
        int p = (oh + 1) & 1, q = (ow + 1) & 1;
        int ihs[2] = { (oh + 1 - p) >> 1, (oh - 1 - p) >> 1 };
        int khs[2] = { p, p + 2 };
        int iws[2] = { (ow + 1 - q) >> 1, (ow - 1 - q) >> 1 };
        int kws[2] = { q, q + 2 };
        for (int a = 0; a < 2; a++) {
            int ih = ihs[a];
            if (ih < 0 || ih >= HI) continue;
            for (int c2 = 0; c2 < 2; c2++) {
                int iw = iws[c2];
                if (iw < 0 || iw >= WI) continue;
                const float* xp = xb + ih * WI + iw;
                const float* wp = w4 + (o2 * 4 + khs[a]) * 4 + kws[c2];  // ci-stride 2048
                #pragma unroll 4
                for (int ci = 0; ci < CIN; ci++)
                    acc += xp[ci * (HI * WI)] * wp[ci * 2048];
            }
        }
    }
    h[idx] = acc;
}

// ---------------- channel LayerNorm: 64 positions x 4 channel-groups per block ----
__global__ __launch_bounds__(256) void k_ln(const float* __restrict__ h,
                                            const float* __restrict__ gam,
                                            const float* __restrict__ bet,
                                            float* __restrict__ xn) {
    int tid = threadIdx.x;
    int pl = tid & 63, cg = tid >> 6;
    int pos = blockIdx.x * 64 + pl;           // (b*H + y)*W + x, < 65536
    int b = pos >> 15, img = pos & 32767;
    const float* hp = h + ((size_t)b * C_ << 15) + img;
    float s1 = 0.f, s2 = 0.f;
    for (int i = 0; i < 64; i++) {
        float v = hp[(size_t)(cg * 64 + i) << 15];
        s1 += v; s2 += v * v;
    }
    __shared__ float ps1[4][64], ps2[4][64];
    ps1[cg][pl] = s1; ps2[cg][pl] = s2;
    __syncthreads();
    float t1 = ps1[0][pl] + ps1[1][pl] + ps1[2][pl] + ps1[3][pl];
    float t2 = ps2[0][pl] + ps2[1][pl] + ps2[2][pl] + ps2[3][pl];
    float mu = t1 * (1.f / 256.f);
    float var = t2 * (1.f / 256.f) - mu * mu;
    float rs = rsqrtf(var + 1e-5f);
    float* xp = xn + ((size_t)b * C_ << 15) + img;
    for (int i = 0; i < 64; i++) {
        int c = cg * 64 + i;
        float v = hp[(size_t)c << 15];
        xp[(size_t)c << 15] = (v - mu) * rs * gam[c] + bet[c];
    }
}

// ---------------- QKV projection per half-window (32 tokens) ----------------
// out layout per window: [which(3)][head(8)][d(32)][l(64)]
__global__ __launch_bounds__(256) void k_qkv(const float* __restrict__ xn,
                                             const float* __restrict__ wqkv,
                                             float* __restrict__ qkv,
                                             int win0, int shift) {
    __shared__ float4 xs4[32][65];           // [l][c/4], row stride 260 floats
    float* xsf = (float*)xs4;
    int blk = blockIdx.x;
    int winl = blk >> 1, half = blk & 1;
    int win = win0 + winl;
    int b = win >> 9, wy = (win >> 5) & 15, wx = win & 31;
    for (int rep = 0; rep < 32; rep++) {
        int flat = rep * 256 + threadIdx.x;  // 8192 = 32 l x 256 c
        int l = flat & 31, c = flat >> 5;
        int gl = half * 32 + l;
        int ly = gl >> 3, lx = gl & 7;
        int y  = (wy * 8 + ly + shift) & 127;
        int xx = (wx * 8 + lx + shift) & 255;
        xsf[l * 260 + c] = xn[(((size_t)b * C_ + c) << 15) + y * 256 + xx];
    }
    __syncthreads();
    int l = threadIdx.x & 31, ocg = threadIdx.x >> 5;
    int gl = half * 32 + l;
    float* outp = qkv + (size_t)winl * QKV_WIN;
    const float4* xv = xs4[l];
    for (int i = 0; i < 96; i++) {
        int oc = ocg * 96 + i;
        const float4* wp = (const float4*)(wqkv + (size_t)oc * 256);
        float acc = 0.f;
        #pragma unroll 16
        for (int c4 = 0; c4 < 64; c4++) {
            float4 xq = xv[c4], wq = wp[c4];
            acc += xq.x * wq.x; acc += xq.y * wq.y;
            acc += xq.z * wq.z; acc += xq.w * wq.w;
        }
        int which = oc >> 8, rem = oc & 255, head = rem >> 5, d = rem & 31;
        outp[(size_t)(((which * 8 + head) * 32 + d) << 6) + gl] = acc;
    }
}

// ---------------- attention: 1 wave per (window, head) ----------------
__global__ __launch_bounds__(64) void k_attn(const float* __restrict__ qkv,
                                             const float* __restrict__ rope,
                                             float* __restrict__ ao) {
    __shared__ float ks[32][64], vs[32][64];
    int winl = blockIdx.x >> 3, head = blockIdx.x & 7;
    const float* base = qkv + (size_t)winl * QKV_WIN;
    const float* qg = base + (size_t)(0 * 8 + head) * 2048;
    const float* kg = base + (size_t)(1 * 8 + head) * 2048;
    const float* vg = base + (size_t)(2 * 8 + head) * 2048;
    int l = threadIdx.x;
    float qr[32];
    #pragma unroll
    for (int r = 0; r < 32; r++) {
        ks[r][l] = kg[r * 64 + l];
        vs[r][l] = vg[r * 64 + l];
        qr[r]    = qg[r * 64 + l];
    }
    __syncthreads();
    const float* cosT = rope + l * 32;
    const float* sinT = rope + 2048 + l * 32;
    const float scale = 0.17677669529663687f;   // 32^-0.5
    #pragma unroll
    for (int d = 0; d < 16; d++) {              // RoPE on q (registers)
        float cs = cosT[d], sn = sinT[d];
        float a = qr[d], bb = qr[d + 16];
        qr[d]      = (a * cs - bb * sn) * scale;
        qr[d + 16] = (bb * cs + a * sn) * scale;
    }
    #pragma unroll
    for (int d = 0; d < 16; d++) {              // RoPE on k column l (LDS)
        float cs = cosT[d], sn = sinT[d];
        float a = ks[d][l], bb = ks[d + 16][l];
        ks[d][l]      = a * cs - bb * sn;
        ks[d + 16][l] = bb * cs + a * sn;
    }
    __syncthreads();
    float s[64];
    #pragma unroll
    for (int j = 0; j < 64; j++) {
        float acc = 0.f;
        #pragma unroll
        for (int d = 0; d < 32; d++) acc += qr[d] * ks[d][j];
        s[j] = acc;
    }
    float m = s[0];
    #pragma unroll
    for (int j = 1; j < 64; j++) m = fmaxf(m, s[j]);
    float sum = 0.f;
    #pragma unroll
    for (int j = 0; j < 64; j++) { s[j] = __expf(s[j] - m); sum += s[j]; }
    float inv = 1.f / sum;
    float* aop = ao + ((size_t)winl * 64 + l) * C_ + head * 32;
    for (int d0 = 0; d0 < 32; d0++) {
        float acc = 0.f;
        #pragma unroll
        for (int j = 0; j < 64; j++) acc += s[j] * vs[d0][j];
        aop[d0] = acc * inv;
    }
}

// ---------------- output projection + residual add ----------------
__global__ __launch_bounds__(256) void k_proj(const float* __restrict__ ao,
                                              const float* __restrict__ wout,
                                              const float* __restrict__ bout,
                                              float* __restrict__ h,
                                              int win0, int shift) {
    __shared__ float4 as4[32][65];
    float* asf = (float*)as4;
    int blk = blockIdx.x;
    int winl = blk >> 1, half = blk & 1;
    int win = win0 + winl;
    for (int rep = 0; rep < 32; rep++) {
        int flat = rep * 256 + threadIdx.x;  // 8192 = 32 l x 256 c (c fastest: coalesced)
        int c = flat & 255, l = flat >> 8;
        asf[l * 260 + c] = ao[((size_t)winl * 64 + half * 32 + l) * C_ + c];
    }
    __syncthreads();
    int l = threadIdx.x & 31, ocg = threadIdx.x >> 5;
    int gl = half * 32 + l;
    int b = win >> 9, wy = (win >> 5) & 15, wx = win & 31;
    int ly = gl >> 3, lx = gl & 7;
    int y  = (wy * 8 + ly + shift) & 127;
    int xx = (wx * 8 + lx + shift) & 255;
    float* hp = h + ((size_t)b * C_ << 15) + y * 256 + xx;
    const float4* xv = as4[l];
    for (int i = 0; i < 32; i++) {
        int oc = ocg * 32 + i;
        const float4* wp = (const float4*)(wout + (size_t)oc * 256);
        float acc = bout[oc];
        #pragma unroll 16
        for (int c4 = 0; c4 < 64; c4++) {
            float4 xq = xv[c4], wq = wp[c4];
            acc += xq.x * wq.x; acc += xq.y * wq.y;
            acc += xq.z * wq.z; acc += xq.w * wq.w;
        }
        hp[(size_t)oc << 15] += acc;
    }
}

// ---------------- fused FF block (LN input xn -> gelu MLP -> h +=) ----------------
__global__ __launch_bounds__(256) void k_ff(const float* __restrict__ xn,
                                            const float* __restrict__ w1,
                                            const float* __restrict__ b1,
                                            const float* __restrict__ w2,
                                            const float* __restrict__ b2,
                                            float* __restrict__ h) {
    __shared__ float4 xs4[32][65];
    __shared__ float hs[32][65];
    float* xsf = (float*)xs4;
    int tid = threadIdx.x;
    int tok0 = blockIdx.x * 32;
    for (int rep = 0; rep < 32; rep++) {
        int flat = rep * 256 + tid;
        int l = flat & 31, c = flat >> 5;
        int pos = tok0 + l;
        int b = pos >> 15, img = pos & 32767;
        xsf[l * 260 + c] = xn[(((size_t)b * C_ + c) << 15) + img];
    }
    __syncthreads();
    int l = tid & 31, og = tid >> 5;
    float acc[32];
    #pragma unroll
    for (int i = 0; i < 32; i++) acc[i] = 0.f;
    const float4* xv = xs4[l];
    for (int jc = 0; jc < 16; jc++) {
        float hv[8];
        #pragma unroll
        for (int ji = 0; ji < 8; ji++) {
            int j = jc * 64 + og * 8 + ji;
            const float4* wp = (const float4*)(w1 + (size_t)j * 256);
            float a = b1[j];
            #pragma unroll 16
            for (int c4 = 0; c4 < 64; c4++) {
                float4 xq = xv[c4], wq = wp[c4];
                a += xq.x * wq.x; a += xq.y * wq.y;
                a += xq.z * wq.z; a += xq.w * wq.w;
            }
            // tanh-approx gelu (jax.nn.gelu default)
            float u = 0.7978845608028654f * (a + 0.044715f * a * a * a);
            hv[ji] = 0.5f * a * (1.f + tanhf(u));
        }
        __syncthreads();   // previous-iteration hs reads complete
        #pragma unroll
        for (int ji = 0; ji < 8; ji++) hs[l][og * 8 + ji] = hv[ji];
        __syncthreads();
        #pragma unroll 4
        for (int j = 0; j < 64; j++) {
            float hj = hs[l][j];
            const float* wp2 = w2 + jc * 64 + j;   // w2[oc][1024]
            #pragma unroll
            for (int i = 0; i < 32; i++)
                acc[i] += hj * wp2[(size_t)(og * 32 + i) * 1024];
        }
        __syncthreads();
    }
    int pos = tok0 + l;
    int b = pos >> 15, img = pos & 32767;
    float* hp = h + ((size_t)b * C_ << 15) + img;
    #pragma unroll
    for (int i = 0; i < 32; i++) {
        int oc = og * 32 + i;
        hp[(size_t)oc << 15] += acc[i] + b2[oc];
    }
}

// ---------------- host launch ----------------
extern "C" void kernel_launch(void* const* d_in, const int* in_sizes, int n_in,
                              void* d_out, int out_size, void* d_ws, size_t ws_size,
                              hipStream_t stream) {
    const float* x      = (const float*)d_in[0];
    const float* ct_w2  = (const float*)d_in[1];
    const float* ct_b2  = (const float*)d_in[2];
    const float* ct_w4  = (const float*)d_in[3];
    const float* ct_b4  = (const float*)d_in[4];
    // dict order: a1(5-9), a2(10-14), f1(15-20), f2(21-26)
    const float* ag[2]  = {(const float*)d_in[5],  (const float*)d_in[10]};
    const float* abt[2] = {(const float*)d_in[6],  (const float*)d_in[11]};
    const float* awq[2] = {(const float*)d_in[7],  (const float*)d_in[12]};
    const float* awo[2] = {(const float*)d_in[8],  (const float*)d_in[13]};
    const float* abo[2] = {(const float*)d_in[9],  (const float*)d_in[14]};
    const float* fg[2]  = {(const float*)d_in[15], (const float*)d_in[21]};
    const float* fbt[2] = {(const float*)d_in[16], (const float*)d_in[22]};
    const float* fw1[2] = {(const float*)d_in[17], (const float*)d_in[23]};
    const float* fb1[2] = {(const float*)d_in[18], (const float*)d_in[24]};
    const float* fw2[2] = {(const float*)d_in[19], (const float*)d_in[25]};
    const float* fb2[2] = {(const float*)d_in[20], (const float*)d_in[26]};

    float* h  = (float*)d_out;
    float* ws = (float*)d_ws;
    float* rope = ws;
    float* xn   = ws + 4096;
    float* qkvb = xn + (size_t)B_ * C_ * IMG;

    // size attention chunk to fit remaining workspace
    size_t used = 4096 + (size_t)B_ * C_ * IMG;
    size_t avail = (ws_size / 4 > used) ? (ws_size / 4 - used) : 0;
    int chunk = 256;
    while (chunk > 16 && (size_t)chunk * (QKV_WIN + 64 * C_) > avail) chunk >>= 1;
    float* aob = qkvb + (size_t)chunk * QKV_WIN;

    k_rope<<<8, 256, 0, stream>>>(rope);
    k_convt<<<(B_ * C_ * H_ * W_) / 256, 256, 0, stream>>>(x, ct_w2, ct_b2, ct_w4, ct_b4, h);

    for (int blk = 0; blk < 2; blk++) {
        int shift = (blk == 0) ? 0 : 4;
        // ----- windowed attention + residual -----
        k_ln<<<(B_ * IMG) / 64, 256, 0, stream>>>(h, ag[blk], abt[blk], xn);
        for (int win0 = 0; win0 < NWIN; win0 += chunk) {
            k_qkv<<<chunk * 2, 256, 0, stream>>>(xn, awq[blk], qkvb, win0, shift);
            k_attn<<<chunk * 8, 64, 0, stream>>>(qkvb, rope, aob);
            k_proj<<<chunk * 2, 256, 0, stream>>>(aob, awo[blk], abo[blk], h, win0, shift);
        }
        // ----- feed-forward + residual -----
        k_ln<<<(B_ * IMG) / 64, 256, 0, stream>>>(h, fg[blk], fbt[blk], xn);
        k_ff<<<(B_ * IMG) / 32, 256, 0, stream>>>(xn, fw1[blk], fb1[blk], fw2[blk], fb2[blk], h);
    }
}

// Round 3
// 2399.875 us; speedup vs baseline: 8.2529x; 8.2529x over previous
//
#include <hip/hip_runtime.h>
#include <hip/hip_bf16.h>
#include <math.h>

typedef __bf16 bf16_t;
typedef __bf16 bf16x8 __attribute__((ext_vector_type(8)));
typedef float  f32x4 __attribute__((ext_vector_type(4)));

// ---------------- problem constants ----------------
constexpr int B_  = 2;
constexpr int CIN = 512, HI = 64, WI = 128;   // conv-transpose input
constexpr int C_  = 256, H_ = 128, W_ = 256;  // residual stream
constexpr int NTOK = B_ * H_ * W_;            // 65536 tokens
constexpr int NWIN = 1024;                    // B * 16 * 32 windows of 8x8

__device__ __forceinline__ unsigned short f2bu(float x) {
    return __builtin_bit_cast(unsigned short, (bf16_t)x);
}

// ---------------- RoPE table: rope[0..2047]=cos, [2048..4095]=sin, idx = l*32+d ----
__global__ __launch_bounds__(256) void k_rope(float* __restrict__ rope) {
    int i = blockIdx.x * 256 + threadIdx.x;
    if (i >= 2048) return;
    int l = i >> 5, d = i & 31;
    int j = d & 15;
    int ly = l >> 3, lx = l & 7;
    float fr = powf(10000.f, -(float)(j & 7) / 8.f);
    float t = (j < 8 ? (float)ly : (float)lx) * fr;
    rope[i]        = cosf(t);
    rope[2048 + i] = sinf(t);
}

// ---------------- multi-segment fp32 -> bf16 convert ----------------
struct CvtSeg { const float* s; bf16_t* d; unsigned n; };
struct CvtParams { CvtSeg seg[9]; };

__global__ __launch_bounds__(256) void k_cvt(CvtParams P) {
    unsigned base = (blockIdx.x * 256u + threadIdx.x) * 4u;
    for (int s = 0; s < 9; s++) {
        unsigned n = P.seg[s].n;
        if (base < n) {
            float4 v = *(const float4*)(P.seg[s].s + base);
            ushort4 o;
            o.x = f2bu(v.x); o.y = f2bu(v.y); o.z = f2bu(v.z); o.w = f2bu(v.w);
            *(ushort4*)(P.seg[s].d + base) = o;
            return;
        }
        base -= n;
    }
}

// ---------------- build conv B-matrices (4 parities x 256 x 2048) + bias ----------
// k = t*512 + ci ; t = a*2 + c ; taps: dh = rp-1+a, dw = rq-1+c
__global__ __launch_bounds__(256) void k_bmat(const float* __restrict__ w2,
                                              const float* __restrict__ w4,
                                              const float* __restrict__ cb2,
                                              const float* __restrict__ cb4,
                                              bf16_t* __restrict__ convB,
                                              float* __restrict__ cbias) {
    int idx = blockIdx.x * 256 + threadIdx.x;     // 4*256*2048 = 2097152
    int k = idx & 2047, o = (idx >> 11) & 255, p = idx >> 19;
    int ci = k & 511, t = k >> 9;
    int rp = p >> 1, rq = p & 1, a = t >> 1, c = t & 1;
    float val;
    if (o < 128) {
        val = (a == 1 - rp && c == 1 - rq)
            ? w2[((ci * 128 + o) * 2 + rp) * 2 + rq] : 0.f;
    } else {
        int kh = 3 - rp - 2 * a, kw = 3 - rq - 2 * c;
        val = w4[((ci * 128 + (o - 128)) * 4 + kh) * 4 + kw];
    }
    convB[idx] = (bf16_t)val;
    if (idx < 256) cbias[idx] = idx < 128 ? cb2[idx] : cb4[idx - 128];
}

// ---------------- im2col for conv parity GEMM ----------------
// Abuf[mlocal][2048], m = b*8192 + u*128 + v (chunk offset mc0)
__global__ __launch_bounds__(256) void k_im2col(const bf16_t* __restrict__ xb,
                                                bf16_t* __restrict__ Abuf,
                                                int mc0, int par) {
    int rp = par >> 1, rq = par & 1;
    int bidx = blockIdx.x;
    int ci0 = (bidx & 7) * 64;
    int t   = (bidx >> 3) & 3;
    int mb  = bidx >> 5;
    int mg0 = mc0 + mb * 128;
    int b = mg0 >> 13, u = (mg0 >> 7) & 63;
    int dh = rp - 1 + (t >> 1), dw = rq - 1 + (t & 1);
    int uu = u + dh;
    __shared__ bf16_t tile[64][128];
    int tid = threadIdx.x;
    int ci_i = tid >> 2, seg = (tid & 3) * 32;
    if (uu < 0 || uu >= HI) {
        for (int j = 0; j < 32; j++) tile[ci_i][seg + j] = (bf16_t)0.f;
    } else {
        const bf16_t* src = xb + ((size_t)b * CIN + ci0 + ci_i) * (HI * WI) + uu * WI;
        for (int j = 0; j < 32; j++) {
            int vv = seg + j + dw;
            tile[ci_i][seg + j] = (vv >= 0 && vv < WI) ? src[vv] : (bf16_t)0.f;
        }
    }
    __syncthreads();
    // each thread writes a full 32-ci span for one output row v  (FIX: c8<8)
    int v = tid >> 1, half = (tid & 1) * 32;
    bf16_t* dst = Abuf + (size_t)(mb * 128 + v) * 2048 + t * 512 + ci0 + half;
    #pragma unroll
    for (int c8 = 0; c8 < 8; c8++) {
        union { uint2 q; unsigned short us[4]; } pk;
        #pragma unroll
        for (int j = 0; j < 4; j++)
            pk.us[j] = __builtin_bit_cast(unsigned short, tile[half + c8 * 4 + j][v]);
        *(uint2*)(dst + c8 * 4) = pk.q;
    }
}

// ---------------- window <-> raw position mapping ----------------
__device__ __forceinline__ int winmap_pos(int idx, int shift) {
    int win = idx >> 6, l = idx & 63;
    int b = win >> 9, wy = (win >> 5) & 15, wx = win & 31;
    int y = ((wy << 3) + (l >> 3) + shift) & 127;
    int x = ((wx << 3) + (l & 7) + shift) & 255;
    return (b << 15) + (y << 8) + x;
}

__device__ __forceinline__ float gelu_tanh(float x) {
    float u = 0.7978845608028654f * (x + 0.044715f * x * x * x);
    return 0.5f * x * (1.f + tanhf(u));
}

// XOR-swizzled LDS byte offset for a [128][64] bf16 tile (row stride 128B).
// Same involution on write and read sides (T2, m214-style).
__device__ __forceinline__ int swz(int row, int byteoff) {
    return (row << 7) + (byteoff ^ ((row & 7) << 4));
}

// ---------------- MFMA GEMM: C(MxN) = A(MxK) * Bw(NxK)^T ----------------
// MODE 0: store bf16 C (ldc), no bias            (QKV)
// MODE 1: Hres[winmap(m_base+m,shift)*256+n] += acc + bias[n]   (attn proj)
// MODE 2: store bf16 gelu(acc+bias) (ldc)        (FF1)
// MODE 3: Hres[(m_base+m)*256+n] += acc + bias[n]               (FF2)
// MODE 4: conv scatter: Hres[pos*256+n] = acc + bias[n], pshift=parity
template<int MODE>
__global__ __launch_bounds__(256) void k_gemm(
    const bf16_t* __restrict__ A, const bf16_t* __restrict__ Bw,
    const float* __restrict__ bias, bf16_t* __restrict__ Cb,
    float* __restrict__ Hres, int K, int ldc, int m_base, int pshift)
{
    __shared__ bf16_t As[128 * 64];
    __shared__ bf16_t Bs[128 * 64];
    char* Asb = (char*)As;
    char* Bsb = (char*)Bs;
    const int tid = threadIdx.x;
    const int m0 = blockIdx.y << 7, n0 = blockIdx.x << 7;
    const int w = tid >> 6, l = tid & 63;
    const int wm = (w >> 1) << 6, wn = (w & 1) << 6;
    const int r16 = l & 15, r4 = l >> 4;
    const int arow = tid >> 3, abyte = (tid & 7) << 4;

    const bf16_t* Ag = A + (size_t)(m0 + arow) * K + ((tid & 7) << 3);
    const bf16_t* Bg = Bw + (size_t)(n0 + arow) * K + ((tid & 7) << 3);

    f32x4 acc[4][4] = {};
    uint4 ra[4], rb[4];
    #pragma unroll
    for (int i = 0; i < 4; i++) {
        ra[i] = *(const uint4*)(Ag + (size_t)(i << 5) * K);
        rb[i] = *(const uint4*)(Bg + (size_t)(i << 5) * K);
    }
    for (int kt = 0; kt < K; kt += 64) {
        __syncthreads();
        #pragma unroll
        for (int i = 0; i < 4; i++) {
            *(uint4*)(Asb + swz(arow + (i << 5), abyte)) = ra[i];
            *(uint4*)(Bsb + swz(arow + (i << 5), abyte)) = rb[i];
        }
        __syncthreads();
        if (kt + 64 < K) {
            #pragma unroll
            for (int i = 0; i < 4; i++) {
                ra[i] = *(const uint4*)(Ag + (size_t)(i << 5) * K + kt + 64);
                rb[i] = *(const uint4*)(Bg + (size_t)(i << 5) * K + kt + 64);
            }
        }
        #pragma unroll
        for (int kk = 0; kk < 2; kk++) {
            bf16x8 af[4], bfr[4];
            #pragma unroll
            for (int f = 0; f < 4; f++)
                af[f] = *(const bf16x8*)(Asb + swz(wm + (f << 4) + r16, (kk << 6) + (r4 << 4)));
            #pragma unroll
            for (int f = 0; f < 4; f++)
                bfr[f] = *(const bf16x8*)(Bsb + swz(wn + (f << 4) + r16, (kk << 6) + (r4 << 4)));
            #pragma unroll
            for (int fm = 0; fm < 4; fm++)
                #pragma unroll
                for (int fn = 0; fn < 4; fn++)
                    acc[fm][fn] = __builtin_amdgcn_mfma_f32_16x16x32_bf16(
                        af[fm], bfr[fn], acc[fm][fn], 0, 0, 0);
        }
    }
    #pragma unroll
    for (int fn = 0; fn < 4; fn++) {
        const int col = n0 + wn + (fn << 4) + r16;
        float bi = 0.f;
        if constexpr (MODE != 0) bi = bias[col];
        #pragma unroll
        for (int fm = 0; fm < 4; fm++) {
            f32x4 v = acc[fm][fn];
            #pragma unroll
            for (int j = 0; j < 4; j++) {
                int mr = m0 + wm + (fm << 4) + (r4 << 2) + j;
                float val = v[j] + bi;
                if constexpr (MODE == 0) {
                    Cb[(size_t)mr * ldc + col] = (bf16_t)val;
                } else if constexpr (MODE == 2) {
                    Cb[(size_t)mr * ldc + col] = (bf16_t)gelu_tanh(val);
                } else if constexpr (MODE == 1) {
                    int pos = winmap_pos(m_base + mr, pshift);
                    Hres[((size_t)pos << 8) + col] += val;
                } else if constexpr (MODE == 3) {
                    Hres[((size_t)(m_base + mr) << 8) + col] += val;
                } else {
                    int mg = m_base + mr;
                    int b = mg >> 13, u = (mg >> 7) & 63, vv = mg & 127;
                    int rp = pshift >> 1, rq = pshift & 1;
                    int pos = (b << 15) + ((((u << 1) + rp)) << 8) + (vv << 1) + rq;
                    Hres[((size_t)pos << 8) + col] = val;
                }
            }
        }
    }
}

// ---------------- channel LayerNorm on token-major h -> bf16 xn ----------------
// windowed=1: write rows in window order (inverse roll by shift)
__global__ __launch_bounds__(256) void k_ln(const float* __restrict__ h,
                                            const float* __restrict__ g,
                                            const float* __restrict__ bt,
                                            bf16_t* __restrict__ xn,
                                            int windowed, int shift) {
    int tok = (blockIdx.x << 2) + (threadIdx.x >> 6);
    int l = threadIdx.x & 63;
    float4 v = *(const float4*)(h + ((size_t)tok << 8) + (l << 2));
    float s  = v.x + v.y + v.z + v.w;
    float s2 = v.x * v.x + v.y * v.y + v.z * v.z + v.w * v.w;
    #pragma unroll
    for (int o = 32; o > 0; o >>= 1) { s += __shfl_xor(s, o); s2 += __shfl_xor(s2, o); }
    float mu = s * (1.f / 256.f);
    float rs = rsqrtf(s2 * (1.f / 256.f) - mu * mu + 1e-5f);
    int orow = tok;
    if (windowed) {
        int b = tok >> 15, img = tok & 32767;
        int y2 = ((img >> 8) - shift) & 127;
        int x2 = ((img & 255) - shift) & 255;
        orow = (((b << 9) + ((y2 >> 3) << 5) + (x2 >> 3)) << 6) + ((y2 & 7) << 3) + (x2 & 7);
    }
    int c = l << 2;
    float4 gv = *(const float4*)(g + c);
    float4 bv = *(const float4*)(bt + c);
    ushort4 o;
    o.x = f2bu((v.x - mu) * rs * gv.x + bv.x);
    o.y = f2bu((v.y - mu) * rs * gv.y + bv.y);
    o.z = f2bu((v.z - mu) * rs * gv.z + bv.z);
    o.w = f2bu((v.w - mu) * rs * gv.w + bv.w);
    *(ushort4*)(xn + ((size_t)orow << 8) + c) = o;
}

// ---------------- attention: 1 wave per (window, head), qkv window-major bf16 ----
__global__ __launch_bounds__(64) void k_attn(const bf16_t* __restrict__ qkv,
                                             const float* __restrict__ rope,
                                             bf16_t* __restrict__ ao) {
    __shared__ float ks[32][64], vs[32][64];
    int winl = blockIdx.x >> 3, head = blockIdx.x & 7;
    int l = threadIdx.x;
    const bf16_t* rowp = qkv + (size_t)(winl * 64 + l) * 768 + head * 32;
    bf16x8 qv[4], kv[4], vv[4];
    #pragma unroll
    for (int i = 0; i < 4; i++) {
        qv[i] = *(const bf16x8*)(rowp + i * 8);
        kv[i] = *(const bf16x8*)(rowp + 256 + i * 8);
        vv[i] = *(const bf16x8*)(rowp + 512 + i * 8);
    }
    float q[32], kf[32];
    #pragma unroll
    for (int i = 0; i < 4; i++)
        #pragma unroll
        for (int e = 0; e < 8; e++) {
            q[i * 8 + e]  = (float)qv[i][e];
            kf[i * 8 + e] = (float)kv[i][e];
        }
    const float* cosT = rope + l * 32;
    const float* sinT = rope + 2048 + l * 32;
    const float scale = 0.17677669529663687f;
    #pragma unroll
    for (int d = 0; d < 16; d++) {
        float cs = cosT[d], sn = sinT[d];
        float a = q[d], b = q[d + 16];
        q[d]      = (a * cs - b * sn) * scale;
        q[d + 16] = (b * cs + a * sn) * scale;
        float ak = kf[d], bk = kf[d + 16];
        kf[d]      = ak * cs - bk * sn;
        kf[d + 16] = bk * cs + ak * sn;
    }
    #pragma unroll
    for (int d = 0; d < 32; d++) {
        ks[d][l] = kf[d];
        vs[d][l] = (float)vv[d >> 3][d & 7];
    }
    __syncthreads();
    float s[64];
    #pragma unroll
    for (int j = 0; j < 64; j++) {
        float a = 0.f;
        #pragma unroll
        for (int d = 0; d < 32; d++) a += q[d] * ks[d][j];
        s[j] = a;
    }
    float m = s[0];
    #pragma unroll
    for (int j = 1; j < 64; j++) m = fmaxf(m, s[j]);
    float sum = 0.f;
    #pragma unroll
    for (int j = 0; j < 64; j++) { s[j] = __expf(s[j] - m); sum += s[j]; }
    float inv = 1.f / sum;
    bf16_t* aop = ao + (size_t)(winl * 64 + l) * 256 + head * 32;
    #pragma unroll
    for (int d0 = 0; d0 < 32; d0 += 4) {
        ushort4 pk;
        float r[4];
        #pragma unroll
        for (int e = 0; e < 4; e++) {
            float a = 0.f;
            #pragma unroll
            for (int j = 0; j < 64; j++) a += s[j] * vs[d0 + e][j];
            r[e] = a * inv;
        }
        pk.x = f2bu(r[0]); pk.y = f2bu(r[1]); pk.z = f2bu(r[2]); pk.w = f2bu(r[3]);
        *(ushort4*)(aop + d0) = pk;
    }
}

// ---------------- per-batch transpose: src[32768 tok][256 c] -> dst[256 c][32768] --
__global__ __launch_bounds__(256) void k_tr(const float* __restrict__ src,
                                            float* __restrict__ dst) {
    __shared__ float t[64][65];
    int tx = blockIdx.x & 3;
    int ty = blockIdx.x >> 2;
    int tid = threadIdx.x;
    int c = (tx << 6) + (tid & 63), r = tid >> 6;
    #pragma unroll
    for (int i = 0; i < 16; i++)
        t[r + i * 4][tid & 63] = src[(size_t)((ty << 6) + r + i * 4) * 256 + c];
    __syncthreads();
    int tok = (ty << 6) + (tid & 63);
    int c2 = tid >> 6;
    #pragma unroll
    for (int i = 0; i < 16; i++)
        dst[(size_t)((tx << 6) + c2 + i * 4) * 32768 + tok] = t[tid & 63][c2 + i * 4];
}

// ---------------- host launch ----------------
extern "C" void kernel_launch(void* const* d_in, const int* in_sizes, int n_in,
                              void* d_out, int out_size, void* d_ws, size_t ws_size,
                              hipStream_t stream) {
    const float* x     = (const float*)d_in[0];
    const float* ct_w2 = (const float*)d_in[1];
    const float* ct_b2 = (const float*)d_in[2];
    const float* ct_w4 = (const float*)d_in[3];
    const float* ct_b4 = (const float*)d_in[4];
    const float* ag[2]  = {(const float*)d_in[5],  (const float*)d_in[10]};
    const float* abt[2] = {(const float*)d_in[6],  (const float*)d_in[11]};
    const float* awq[2] = {(const float*)d_in[7],  (const float*)d_in[12]};
    const float* awo[2] = {(const float*)d_in[8],  (const float*)d_in[13]};
    const float* abo[2] = {(const float*)d_in[9],  (const float*)d_in[14]};
    const float* fg[2]  = {(const float*)d_in[15], (const float*)d_in[21]};
    const float* fbt[2] = {(const float*)d_in[16], (const float*)d_in[22]};
    const float* fw1[2] = {(const float*)d_in[17], (const float*)d_in[23]};
    const float* fb1[2] = {(const float*)d_in[18], (const float*)d_in[24]};
    const float* fw2[2] = {(const float*)d_in[19], (const float*)d_in[25]};
    const float* fb2[2] = {(const float*)d_in[20], (const float*)d_in[26]};

    float* h_t = (float*)d_out;   // token-major residual [65536][256] fp32

    char* w = (char*)d_ws;
    auto alloc = [&](size_t bytes) {
        char* p = w; w += (bytes + 255) & ~(size_t)255; return p;
    };
    float*  rope  = (float*)alloc(4096 * 4);
    bf16_t* wqkvb[2] = {(bf16_t*)alloc(196608 * 2), (bf16_t*)alloc(196608 * 2)};
    bf16_t* woutb[2] = {(bf16_t*)alloc(65536 * 2),  (bf16_t*)alloc(65536 * 2)};
    bf16_t* fw1b[2]  = {(bf16_t*)alloc(262144 * 2), (bf16_t*)alloc(262144 * 2)};
    bf16_t* fw2b[2]  = {(bf16_t*)alloc(262144 * 2), (bf16_t*)alloc(262144 * 2)};
    bf16_t* convB = (bf16_t*)alloc((size_t)4 * 524288 * 2);
    float*  cbias = (float*)alloc(256 * 4);
    char*   R1    = alloc(33554432);      // xb (conv) / xn / transpose bounce
    size_t  usedB = (size_t)(w - (char*)d_ws);
    size_t  Sb    = ws_size > usedB ? ws_size - usedB : 0;
    if (Sb > (size_t)134217728) Sb = 134217728;
    char*   S     = w;

    bf16_t* xb = (bf16_t*)R1;
    bf16_t* xn = (bf16_t*)R1;

    auto p2f = [](size_t v) -> size_t { size_t r = 1; while ((r << 1) <= v) r <<= 1; return r; };
    int MC_cv = (int)(Sb / 4096   > 16384 ? 16384 : p2f(Sb / 4096));
    int CW    = (int)(Sb / 131072 > 1024  ? 1024  : p2f(Sb / 131072));
    int MCF   = (int)(Sb / 2048   > 65536 ? 65536 : p2f(Sb / 2048));
    if (MC_cv > 16384) MC_cv = 16384;
    if (CW > 1024) CW = 1024;
    if (MCF > 65536) MCF = 65536;

    // ---- prep: rope, bf16 conversions, conv B-matrices ----
    k_rope<<<8, 256, 0, stream>>>(rope);
    CvtParams P;
    P.seg[0] = { x,       xb,        (unsigned)(B_ * CIN * HI * WI) };
    P.seg[1] = { awq[0],  wqkvb[0],  196608 };
    P.seg[2] = { awq[1],  wqkvb[1],  196608 };
    P.seg[3] = { awo[0],  woutb[0],  65536 };
    P.seg[4] = { awo[1],  woutb[1],  65536 };
    P.seg[5] = { fw1[0],  fw1b[0],   262144 };
    P.seg[6] = { fw1[1],  fw1b[1],   262144 };
    P.seg[7] = { fw2[0],  fw2b[0],   262144 };
    P.seg[8] = { fw2[1],  fw2b[1],   262144 };
    unsigned total4 = (8388608u + 196608u * 2 + 65536u * 2 + 262144u * 4) / 4;
    k_cvt<<<(total4 + 255) / 256, 256, 0, stream>>>(P);
    k_bmat<<<8192, 256, 0, stream>>>(ct_w2, ct_w4, ct_b2, ct_b4, convB, cbias);

    // ---- conv-transpose as 4 parity-class GEMMs (im2col K=2048) ----
    for (int p = 0; p < 4; p++) {
        for (int mc0 = 0; mc0 < 16384; mc0 += MC_cv) {
            int MC = 16384 - mc0 < MC_cv ? 16384 - mc0 : MC_cv;
            k_im2col<<<(MC / 128) * 32, 256, 0, stream>>>(xb, (bf16_t*)S, mc0, p);
            k_gemm<4><<<dim3(2, MC / 128), 256, 0, stream>>>(
                (const bf16_t*)S, convB + (size_t)p * 524288, cbias,
                nullptr, h_t, 2048, 0, mc0, p);
        }
    }

    // ---- two transformer blocks ----
    for (int blk = 0; blk < 2; blk++) {
        int shift = blk ? 4 : 0;
        // windowed attention + residual
        k_ln<<<NTOK / 4, 256, 0, stream>>>(h_t, ag[blk], abt[blk], xn, 1, shift);
        for (int w0 = 0; w0 < NWIN; w0 += CW) {
            bf16_t* qkvc = (bf16_t*)S;
            bf16_t* aoc  = qkvc + (size_t)CW * 64 * 768;
            k_gemm<0><<<dim3(6, CW * 64 / 128), 256, 0, stream>>>(
                xn + (size_t)w0 * 64 * 256, wqkvb[blk], nullptr,
                qkvc, nullptr, 256, 768, 0, 0);
            k_attn<<<CW * 8, 64, 0, stream>>>(qkvc, rope, aoc);
            k_gemm<1><<<dim3(2, CW * 64 / 128), 256, 0, stream>>>(
                aoc, woutb[blk], abo[blk], nullptr, h_t, 256, 0, w0 * 64, shift);
        }
        // feed-forward + residual
        k_ln<<<NTOK / 4, 256, 0, stream>>>(h_t, fg[blk], fbt[blk], xn, 0, 0);
        for (int t0 = 0; t0 < NTOK; t0 += MCF) {
            bf16_t* h1 = (bf16_t*)S;
            k_gemm<2><<<dim3(8, MCF / 128), 256, 0, stream>>>(
                xn + (size_t)t0 * 256, fw1b[blk], fb1[blk],
                h1, nullptr, 256, 1024, 0, 0);
            k_gemm<3><<<dim3(2, MCF / 128), 256, 0, stream>>>(
                h1, fw2b[blk], fb2[blk], nullptr, h_t, 1024, 0, t0, 0);
        }
    }

    // ---- final: token-major fp32 -> NCHW via per-batch bounce ----
    for (int b = 0; b < 2; b++) {
        hipMemcpyAsync(R1, h_t + (size_t)b * 32768 * 256, 33554432,
                       hipMemcpyDeviceToDevice, stream);
        k_tr<<<2048, 256, 0, stream>>>((const float*)R1,
                                       (float*)d_out + (size_t)b * 256 * 32768);
    }
}